// Round 4
// baseline (439.375 us; speedup 1.0000x reference)
//
#include <hip/hip_runtime.h>

// x:   (128, 128, 56, 56) f32     c = 2*k + i2
// w1:  (64, 3, 4) f32             w1[k, tap, j4]
// w2:  (2, 3, 32) f32             w2[i2, tap, j]
// t4:  (128, 8, 3136) f32 in ws   [l][(i2*4+j4)][m*56+o]
// out: (128, 128, 56, 56) f32     out[l][j*4+o4][m][n]
//
// Stage 1: t4[l,i2,m,o,j4] = sum_{k,tap} xroll[l,2k+i2, m+tap-1, o] * w1[k,tap,j4]
//   xroll row h -> src row (h==0?55:h-1), zero outside 0<=h<56.
// Stage 2: out[l, 4j+o4, m, n] = sum_{i2,k} t4[l,i2,m,n+k-1,o4] * w2[i2,k,j]
//   zero-pad n+k-1 outside [0,55].

__global__ __launch_bounds__(256) void stage1_kernel(
    const float* __restrict__ x, const float* __restrict__ w1,
    float* __restrict__ t4)
{
    // grid = 392 blocks (= 8 XCD * 49); swizzle so each XCD gets 49 consecutive
    // blocks (~16 same-l images) -> tap re-reads hit same L2.
    const int bid  = (blockIdx.x & 7) * 49 + (blockIdx.x >> 3);
    const int item = bid * 256 + threadIdx.x;        // [0, 100352)
    const int l  = item / 784;                       // 784 = 56 rows * 14 chunks
    const int r  = item - l * 784;
    const int m  = r / 14;
    const int o0 = (r - m * 14) * 4;                 // float4-aligned

    int   off[3];
    float vf[3];
#pragma unroll
    for (int t = 0; t < 3; ++t) {
        const int h = m + t - 1;                     // rolled-row index
        vf[t] = (h >= 0 && h < 56) ? 1.0f : 0.0f;
        const int row = (h <= 0) ? 55 : (h - 1);     // roll(+1,H); always in-bounds
        off[t] = row * 56 + o0;
    }

    float acc[2][4][4] = {};                         // [i2][j][o-sub]
    const float* xl = x + (size_t)l * (128 * 3136);

    for (int k = 0; k < 64; ++k) {
        float w[3][4];                               // uniform -> s_load
#pragma unroll
        for (int t = 0; t < 3; ++t)
#pragma unroll
            for (int j = 0; j < 4; ++j)
                w[t][j] = w1[(k * 3 + t) * 4 + j] * vf[t];  // fold boundary into w

#pragma unroll
        for (int i2 = 0; i2 < 2; ++i2) {
            const float* xc = xl + (size_t)(2 * k + i2) * 3136;
#pragma unroll
            for (int t = 0; t < 3; ++t) {
                const float4 xv = *reinterpret_cast<const float4*>(xc + off[t]);
#pragma unroll
                for (int j = 0; j < 4; ++j) {
                    acc[i2][j][0] = fmaf(xv.x, w[t][j], acc[i2][j][0]);
                    acc[i2][j][1] = fmaf(xv.y, w[t][j], acc[i2][j][1]);
                    acc[i2][j][2] = fmaf(xv.z, w[t][j], acc[i2][j][2]);
                    acc[i2][j][3] = fmaf(xv.w, w[t][j], acc[i2][j][3]);
                }
            }
        }
    }

    float* tp = t4 + (size_t)l * (8 * 3136) + m * 56 + o0;
#pragma unroll
    for (int i2 = 0; i2 < 2; ++i2)
#pragma unroll
        for (int j = 0; j < 4; ++j) {
            const float4 v = make_float4(acc[i2][j][0], acc[i2][j][1],
                                         acc[i2][j][2], acc[i2][j][3]);
            *reinterpret_cast<float4*>(tp + (size_t)(i2 * 4 + j) * 3136) = v;
        }
}

__global__ __launch_bounds__(256) void stage2_kernel(
    const float* __restrict__ t4, const float* __restrict__ w2,
    float* __restrict__ out)
{
    // block = (l, o4, m-half); grid = 128*4*2 = 1024
    const int l  = blockIdx.x >> 3;
    const int o4 = (blockIdx.x >> 1) & 3;
    const int mh = blockIdx.x & 1;

    __shared__ float lds[2][1568];                   // [i2][28 rows * 56]
    const int tid = threadIdx.x;

    const float* p0 = t4 + ((size_t)l * 8 + 0 + o4) * 3136 + mh * 1568;
    const float* p1 = t4 + ((size_t)l * 8 + 4 + o4) * 3136 + mh * 1568;
    for (int t = tid; t < 784; t += 256) {           // 784 float4 = both planes
        const int i2 = (t >= 392);
        const int p4 = i2 ? t - 392 : t;
        const float4 v = *reinterpret_cast<const float4*>(
            (i2 ? p1 : p0) + (size_t)p4 * 4);
        *reinterpret_cast<float4*>(&lds[i2][p4 * 4]) = v;
    }
    __syncthreads();

    for (int ch = tid; ch < 392; ch += 256) {        // (local row, n-chunk)
        const int ml = ch / 14;
        const int n0 = (ch - ml * 14) * 4;
        const int m  = mh * 28 + ml;

        float tv[2][6];                              // t[m][n0-1 .. n0+4]
#pragma unroll
        for (int i = 0; i < 2; ++i)
#pragma unroll
            for (int d = 0; d < 6; ++d) {
                const int nn = n0 - 1 + d;
                tv[i][d] = (nn >= 0 && nn < 56) ? lds[i][ml * 56 + nn] : 0.0f;
            }

        float* ob = out + ((size_t)l * 128 + o4) * 3136 + m * 56 + n0;
#pragma unroll
        for (int j = 0; j < 32; ++j) {
            float4 s = make_float4(0.f, 0.f, 0.f, 0.f);
#pragma unroll
            for (int i = 0; i < 2; ++i)
#pragma unroll
                for (int k = 0; k < 3; ++k) {
                    const float wv = w2[(i * 3 + k) * 32 + j];   // uniform s_load
                    s.x = fmaf(tv[i][k + 0], wv, s.x);
                    s.y = fmaf(tv[i][k + 1], wv, s.y);
                    s.z = fmaf(tv[i][k + 2], wv, s.z);
                    s.w = fmaf(tv[i][k + 3], wv, s.w);
                }
            *reinterpret_cast<float4*>(ob + (size_t)j * 4 * 3136) = s;  // c=4j+o4
        }
    }
}

extern "C" void kernel_launch(void* const* d_in, const int* in_sizes, int n_in,
                              void* d_out, int out_size, void* d_ws, size_t ws_size,
                              hipStream_t stream)
{
    const float* x  = (const float*)d_in[0];
    const float* w1 = (const float*)d_in[1];
    const float* w2 = (const float*)d_in[2];
    float* out = (float*)d_out;
    float* t4  = (float*)d_ws;                       // 128*8*3136*4 = 12.8 MB

    stage1_kernel<<<dim3(392), dim3(256), 0, stream>>>(x, w1, t4);
    stage2_kernel<<<dim3(1024), dim3(256), 0, stream>>>(t4, w2, out);
}

// Round 5
// 375.925 us; speedup vs baseline: 1.1688x; 1.1688x over previous
//
#include <hip/hip_runtime.h>

// x:   (128, 128, 56, 56) f32     c = 2*k + i2
// w1:  (64, 3, 4) f32             w1[k, tap, j4]
// w2:  (2, 3, 32) f32             w2[i2, tap, j]
// t4:  (128, 8, 3136) f32 in ws   [l][(i2*4+j4)][m*56+o]
// out: (128, 128, 56, 56) f32     out[l][j*4+o4][m][n]
//
// Stage 1: t4[l,i2,m,o,j4] = sum_{k,tap} xroll[l,2k+i2, m+tap-1, o] * w1[k,tap,j4]
//   xroll row h -> src row (h==0?55:h-1), zero outside 0<=h<56.
// Stage 2: out[l, 4j+o4, m, n] = sum_{i2,k} t4[l,i2,m,n+k-1,o4] * w2[i2,k,j]
//
// R4 lesson: stage1 is LATENCY-bound (9% HBM, 7% VALU, 16% occ at 6 waves/CU).
// This version: k-split x4 within the block (wave = 16-k group, lane = float4
// chunk) + LDS partial reduction -> 1568 blocks, ~24 waves/CU, float4 loads kept.

__global__ __launch_bounds__(256) void stage1_kernel(
    const float* __restrict__ x, const float* __restrict__ w1,
    float* __restrict__ t4)
{
    // 1568 = 8 XCD * 196: consecutive p-ranges per XCD for L2 halo reuse
    const int bid   = ((int)blockIdx.x & 7) * 196 + ((int)blockIdx.x >> 3);
    const int tid   = threadIdx.x;
    const int chunk = tid & 63;                       // float4 chunk within block
    const int kg    = __builtin_amdgcn_readfirstlane(tid >> 6);  // wave id = k-group

    const int p4 = bid * 64 + chunk;                  // global chunk [0,100352)
    const int l  = p4 / 784;                          // 784 chunks per image
    const int rc = p4 - l * 784;
    const int m  = rc / 14;
    const int o0 = (rc - m * 14) * 4;

    int   off[3];
    float vf[3];
#pragma unroll
    for (int t = 0; t < 3; ++t) {
        const int h = m + t - 1;                      // rolled-row index
        vf[t] = (h >= 0 && h < 56) ? 1.0f : 0.0f;
        const int row = (h <= 0) ? 55 : (h - 1);      // roll(+1,H); in-bounds clamp
        off[t] = row * 56 + o0;
    }

    float acc[2][4][4] = {};                          // [i2][j][o-sub]
    const float* xl = x + (size_t)l * (128 * 3136);
    const int k0 = kg * 16;

#pragma unroll 4
    for (int kk = 0; kk < 16; ++kk) {
        const int k = k0 + kk;
        float w[3][4];
#pragma unroll
        for (int t = 0; t < 3; ++t)
#pragma unroll
            for (int j = 0; j < 4; ++j)
                w[t][j] = w1[(k * 3 + t) * 4 + j] * vf[t];  // boundary folded in

#pragma unroll
        for (int i2 = 0; i2 < 2; ++i2) {
            const float* xc = xl + (size_t)(2 * k + i2) * 3136;
#pragma unroll
            for (int t = 0; t < 3; ++t) {
                const float4 xv = *reinterpret_cast<const float4*>(xc + off[t]);
#pragma unroll
                for (int j = 0; j < 4; ++j) {
                    acc[i2][j][0] = fmaf(xv.x, w[t][j], acc[i2][j][0]);
                    acc[i2][j][1] = fmaf(xv.y, w[t][j], acc[i2][j][1]);
                    acc[i2][j][2] = fmaf(xv.z, w[t][j], acc[i2][j][2]);
                    acc[i2][j][3] = fmaf(xv.w, w[t][j], acc[i2][j][3]);
                }
            }
        }
    }

    // Partial reduction: waves 1..3 dump partials to LDS; wave 0 accumulates.
    __shared__ float4 lds[3 * 8 * 64];                // [kg-1][out][chunk], 24 KB
    if (kg != 0) {
#pragma unroll
        for (int i2 = 0; i2 < 2; ++i2)
#pragma unroll
            for (int j = 0; j < 4; ++j)
                lds[(((kg - 1) * 8) + (i2 * 4 + j)) * 64 + chunk] =
                    make_float4(acc[i2][j][0], acc[i2][j][1],
                                acc[i2][j][2], acc[i2][j][3]);
    }
    __syncthreads();

    if (kg == 0) {
        float* tp = t4 + (size_t)l * (8 * 3136) + m * 56 + o0;
#pragma unroll
        for (int i2 = 0; i2 < 2; ++i2)
#pragma unroll
            for (int j = 0; j < 4; ++j) {
                const int out = i2 * 4 + j;
                float4 s = make_float4(acc[i2][j][0], acc[i2][j][1],
                                       acc[i2][j][2], acc[i2][j][3]);
#pragma unroll
                for (int g = 0; g < 3; ++g) {
                    const float4 v = lds[(g * 8 + out) * 64 + chunk];
                    s.x += v.x; s.y += v.y; s.z += v.z; s.w += v.w;
                }
                *reinterpret_cast<float4*>(tp + (size_t)out * 3136) = s;
            }
    }
}

__global__ __launch_bounds__(256) void stage2_kernel(
    const float* __restrict__ t4, const float* __restrict__ w2,
    float* __restrict__ out)
{
    // block = (l, o4, m-half); grid = 128*4*2 = 1024
    const int l  = blockIdx.x >> 3;
    const int o4 = (blockIdx.x >> 1) & 3;
    const int mh = blockIdx.x & 1;

    __shared__ float lds[2][1568];                    // [i2][28 rows * 56]
    const int tid = threadIdx.x;

    const float* p0 = t4 + ((size_t)l * 8 + 0 + o4) * 3136 + mh * 1568;
    const float* p1 = t4 + ((size_t)l * 8 + 4 + o4) * 3136 + mh * 1568;
    for (int t = tid; t < 784; t += 256) {            // 784 float4 = both planes
        const int i2 = (t >= 392);
        const int p4 = i2 ? t - 392 : t;
        const float4 v = *reinterpret_cast<const float4*>(
            (i2 ? p1 : p0) + (size_t)p4 * 4);
        *reinterpret_cast<float4*>(&lds[i2][p4 * 4]) = v;
    }
    __syncthreads();

    for (int ch = tid; ch < 392; ch += 256) {         // (local row, n-chunk)
        const int ml = ch / 14;
        const int n0 = (ch - ml * 14) * 4;
        const int m  = mh * 28 + ml;

        float tv[2][6];                               // t[m][n0-1 .. n0+4]
#pragma unroll
        for (int i = 0; i < 2; ++i)
#pragma unroll
            for (int d = 0; d < 6; ++d) {
                const int nn = n0 - 1 + d;
                tv[i][d] = (nn >= 0 && nn < 56) ? lds[i][ml * 56 + nn] : 0.0f;
            }

        float* ob = out + ((size_t)l * 128 + o4) * 3136 + m * 56 + n0;
#pragma unroll
        for (int j = 0; j < 32; ++j) {
            float4 s = make_float4(0.f, 0.f, 0.f, 0.f);
#pragma unroll
            for (int i = 0; i < 2; ++i)
#pragma unroll
                for (int k = 0; k < 3; ++k) {
                    const float wv = w2[(i * 3 + k) * 32 + j];    // uniform s_load
                    s.x = fmaf(tv[i][k + 0], wv, s.x);
                    s.y = fmaf(tv[i][k + 1], wv, s.y);
                    s.z = fmaf(tv[i][k + 2], wv, s.z);
                    s.w = fmaf(tv[i][k + 3], wv, s.w);
                }
            *reinterpret_cast<float4*>(ob + (size_t)j * 4 * 3136) = s;  // c=4j+o4
        }
    }
}

extern "C" void kernel_launch(void* const* d_in, const int* in_sizes, int n_in,
                              void* d_out, int out_size, void* d_ws, size_t ws_size,
                              hipStream_t stream)
{
    const float* x  = (const float*)d_in[0];
    const float* w1 = (const float*)d_in[1];
    const float* w2 = (const float*)d_in[2];
    float* out = (float*)d_out;
    float* t4  = (float*)d_ws;                        // 128*8*3136*4 = 12.8 MB

    stage1_kernel<<<dim3(1568), dim3(256), 0, stream>>>(x, w1, t4);
    stage2_kernel<<<dim3(1024), dim3(256), 0, stream>>>(t4, w2, out);
}